// Round 11
// baseline (334.318 us; speedup 1.0000x reference)
//
#include <hip/hip_runtime.h>
#include <math.h>

#define BN 8192
#define ENC 256
#define NCL 32
#define TM 128
#define BK 32
#define PANEL 2048
#define CCAP 1024

typedef __attribute__((ext_vector_type(8))) short short8;   // bf16x8 fragment
typedef __attribute__((ext_vector_type(4))) float f32x4;
typedef __attribute__((ext_vector_type(4))) unsigned uint4v;

__device__ __forceinline__ ushort f2bf(float x) {           // RNE float->bf16
    unsigned b = __float_as_uint(x);
    return (ushort)((b + 0x7FFFu + ((b >> 16) & 1u)) >> 16);
}

__device__ __forceinline__ void async16(void* lds, const void* g) {
    __builtin_amdgcn_global_load_lds(
        (const __attribute__((address_space(1))) unsigned*)g,
        (__attribute__((address_space(3))) unsigned*)lds, 16, 0, 0);
}

// ---------------- K1: sumsq + cat argmax + bf16 hi/lo split (granule-swizzled) ----------
__global__ void prep_kernel(const float* __restrict__ enc, const float* __restrict__ cat,
                            float* __restrict__ sq, float* __restrict__ maxg,
                            int* __restrict__ hard, ushort* __restrict__ eh,
                            ushort* __restrict__ el) {
    int w = threadIdx.x >> 6, l = threadIdx.x & 63;
    int row = blockIdx.x * 4 + w;
    const float4* e4 = (const float4*)(enc + (size_t)row * ENC);
    float4 v = e4[l];  // elements 4l..4l+3
    float s = v.x * v.x + v.y * v.y + v.z * v.z + v.w * v.w;
    for (int m = 32; m; m >>= 1) s += __shfl_xor(s, m, 64);

    ushort4 hh, ll;
    hh.x = f2bf(v.x); ll.x = f2bf(v.x - __uint_as_float((unsigned)hh.x << 16));
    hh.y = f2bf(v.y); ll.y = f2bf(v.y - __uint_as_float((unsigned)hh.y << 16));
    hh.z = f2bf(v.z); ll.z = f2bf(v.z - __uint_as_float((unsigned)hh.z << 16));
    hh.w = f2bf(v.w); ll.w = f2bf(v.w - __uint_as_float((unsigned)hh.w << 16));
    int g = l >> 1;                                       // original granule 0..31
    int gs = (g & ~3) | ((g & 3) ^ ((row >> 1) & 3));     // swizzled within group-of-4
    int kp = gs * 8 + (l & 1) * 4;                        // element offset in row
    *(ushort4*)(eh + (size_t)row * ENC + kp) = hh;
    *(ushort4*)(el + (size_t)row * ENC + kp) = ll;

    float cv = (l < NCL) ? cat[(size_t)row * NCL + l] : -__builtin_huge_valf();
    int ci = (l < NCL) ? l : 0x7fffffff;
    for (int m = 32; m; m >>= 1) {
        float ov = __shfl_xor(cv, m, 64);
        int oi = __shfl_xor(ci, m, 64);
        if (ov > cv || (ov == cv && oi < ci)) { cv = ov; ci = oi; }
    }
    if (l == 0) { sq[row] = s; maxg[row] = cv; hard[row] = ci; }
}

// ---------------- K2: symmetric-tile split-bf16 MFMA distance GEMM --------------------
// Panel p computes only blocks (p, q>=p); diagonal block only tiles J>=I. Each
// mirrored tile is transposed through LDS and written to its symmetric location
// (live for diagonal-block mirrors, stash S[q][p] for off-diagonal). Exact:
// mirrored values are bit-copies. 51% of the original tile count.
__global__ __launch_bounds__(256, 2)
void dist_mfma_kernel(const ushort* __restrict__ eh, const ushort* __restrict__ el,
                      const float* __restrict__ sq, float* __restrict__ live,
                      float* __restrict__ stash, int p) {
    __shared__ __align__(16) char smem[TM * 132 * 4];     // 67584 B: staging / transpose
    ushort* lds0 = (ushort*)smem;                          // [2][4*TM*BK] = 65536 B
    float* T = (float*)smem;                               // [128][132] transpose bounce

    int t = threadIdx.x, w = t >> 6, l = t & 63;
    int wm = w >> 1, wn = w & 1;

    // m204 bijective XCD swizzle (nwg not divisible by 8)
    int nwg = gridDim.x;
    int bid = blockIdx.x;
    int q8 = nwg >> 3, r8 = nwg & 7, xcd = bid & 7, off = bid >> 3;
    int wg = (xcd < r8 ? xcd * (q8 + 1) : r8 * (q8 + 1) + (xcd - r8) * q8) + off;

    // decode wg -> (I, J, q): 136 upper-tri diagonal tiles first, then q-major
    int I, J, q;
    if (wg < 136) {
        int x = wg; I = 0;
        while (x >= 16 - I) { x -= 16 - I; ++I; }
        J = I + x; q = p;
    } else {
        int rem = wg - 136;
        q = p + 1 + (rem >> 8);
        int tt = rem & 255;
        I = tt >> 4; J = tt & 15;
    }
    int li0 = I * TM;                  // panel-local A rows
    int gi0 = p * PANEL + li0;         // global A rows
    int j0 = q * PANEL + J * TM;       // global B rows / dist cols
    bool mir = (q > p) || (J > I);     // tile has a distinct mirror

    f32x4 acc[4][4];
#pragma unroll
    for (int m = 0; m < 4; ++m)
#pragma unroll
        for (int n = 0; n < 4; ++n) acc[m][n] = (f32x4){0.f, 0.f, 0.f, 0.f};

    int srow = w * 32 + (l >> 2);      // staging row (+ q*16), wave covers 32 rows
    int sg = (l & 3) * 8;              // granule elem offset within K-slice

#define STAGE(BUF, K0)                                                       \
    do {                                                                     \
        _Pragma("unroll") for (int q_ = 0; q_ < 2; ++q_) {                   \
            int r_ = srow + q_ * 16;                                         \
            size_t ga_ = (size_t)(gi0 + r_) * ENC + (K0) + sg;               \
            size_t gb_ = (size_t)(j0 + r_) * ENC + (K0) + sg;                \
            int ldo_ = r_ * BK + sg;                                         \
            async16(lds0 + (size_t)(BUF) * 4 * TM * BK + 0 * TM * BK + ldo_, eh + ga_); \
            async16(lds0 + (size_t)(BUF) * 4 * TM * BK + 1 * TM * BK + ldo_, el + ga_); \
            async16(lds0 + (size_t)(BUF) * 4 * TM * BK + 2 * TM * BK + ldo_, eh + gb_); \
            async16(lds0 + (size_t)(BUF) * 4 * TM * BK + 3 * TM * BK + ldo_, el + gb_); \
        }                                                                    \
    } while (0)

    STAGE(0, 0);
    __syncthreads();                   // prologue: wait first tile

    int cur = 0;
    for (int k0 = 0; k0 < ENC; k0 += BK) {
        if (k0 + BK < ENC) STAGE(cur ^ 1, k0 + BK);   // issue next tile FIRST

        const ushort* Ah = lds0 + (size_t)cur * 4 * TM * BK;
        const ushort* Al = Ah + TM * BK;
        const ushort* Bh = Ah + 2 * TM * BK;
        const ushort* Bl = Ah + 3 * TM * BK;

        short8 ah[4], al4[4], bh[4], bl4[4];
#pragma unroll
        for (int m = 0; m < 4; ++m) {
            int R = wm * 64 + m * 16 + (l & 15);
            int gl = (l >> 4) ^ ((R >> 1) & 3);       // un-swizzle on read
            ah[m]  = *(const short8*)(Ah + R * BK + gl * 8);
            al4[m] = *(const short8*)(Al + R * BK + gl * 8);
        }
#pragma unroll
        for (int n = 0; n < 4; ++n) {
            int R = wn * 64 + n * 16 + (l & 15);
            int gl = (l >> 4) ^ ((R >> 1) & 3);
            bh[n]  = *(const short8*)(Bh + R * BK + gl * 8);
            bl4[n] = *(const short8*)(Bl + R * BK + gl * 8);
        }
        // swapped operands: D[col=l&15 -> dist row][reg -> dist col]
#pragma unroll
        for (int m = 0; m < 4; ++m)
#pragma unroll
            for (int n = 0; n < 4; ++n) {
                acc[m][n] = __builtin_amdgcn_mfma_f32_16x16x32_bf16(bh[n],  ah[m],  acc[m][n], 0, 0, 0);
                acc[m][n] = __builtin_amdgcn_mfma_f32_16x16x32_bf16(bl4[n], ah[m],  acc[m][n], 0, 0, 0);
                acc[m][n] = __builtin_amdgcn_mfma_f32_16x16x32_bf16(bh[n],  al4[m], acc[m][n], 0, 0, 0);
            }

        __syncthreads();               // one barrier/step: drains next-tile loads
        cur ^= 1;
    }
#undef STAGE

    // epilogue: i = li0 + m*16 + (l&15), j = j0 + n*16 + (l>>4)*4 + r (swapped layout)
    int il = l & 15, q4 = (l >> 4) * 4;
    float sqi[4];
    float sqj[4][4];
#pragma unroll
    for (int m = 0; m < 4; ++m) sqi[m] = sq[gi0 + wm * 64 + m * 16 + il];
#pragma unroll
    for (int n = 0; n < 4; ++n)
#pragma unroll
        for (int r = 0; r < 4; ++r) sqj[n][r] = sq[j0 + wn * 64 + n * 16 + q4 + r];

#pragma unroll
    for (int m = 0; m < 4; ++m)
#pragma unroll
        for (int n = 0; n < 4; ++n) {
            float4 o;
            o.x = fmaxf(sqi[m] + sqj[n][0] - 2.f * acc[m][n][0], 0.f);
            o.y = fmaxf(sqi[m] + sqj[n][1] - 2.f * acc[m][n][1], 0.f);
            o.z = fmaxf(sqi[m] + sqj[n][2] - 2.f * acc[m][n][2], 0.f);
            o.w = fmaxf(sqi[m] + sqj[n][3] - 2.f * acc[m][n][3], 0.f);
            int lr = wm * 64 + m * 16 + il;           // local row
            int lc = wn * 64 + n * 16 + q4;           // local col
            *(float4*)(live + (size_t)(li0 + lr) * BN + j0 + lc) = o;
            if (mir) *(float4*)(T + lr * 132 + lc) = o;   // bank-safe (2-way)
        }

    if (mir) {
        __syncthreads();               // T complete (staging LDS reads long done)
        float* dstp; size_t dstride; int dcol0;
        if (q == p) { dstp = live;  dstride = BN;    dcol0 = p * PANEL + I * TM; }
        else {
            dstp = stash + (size_t)(q * (q - 1) / 2 + p) * ((size_t)PANEL * PANEL);
            dstride = PANEL; dcol0 = I * TM;
        }
        int drow0 = J * TM;            // rows of the mirror tile (panel-q local)
        int j2 = t & 127, ib = (t >> 7) * 64;
#pragma unroll
        for (int it = 0; it < 16; ++it) {   // each lane fills 64B sectors in order
            int i0 = ib + it * 4;
            float4 o4;
            o4.x = T[(i0 + 0) * 132 + j2];
            o4.y = T[(i0 + 1) * 132 + j2];
            o4.z = T[(i0 + 2) * 132 + j2];
            o4.w = T[(i0 + 3) * 132 + j2];
            *(float4*)(dstp + (size_t)(drow0 + j2) * dstride + dcol0 + i0) = o4;
        }
    }
}

// ---------------- K3: sampling-pivot exact rank select (quarter-segmented) ------------
// Row quarters come from up to 4 buffers (live / stash blocks). Pivot = rank-8
// of 256 samples; one segmented row pass compacts < pivot candidates (~255);
// bisect candidates; bin pass touches candidates only. Fallback exact.
__global__ __launch_bounds__(256, 4)
void select_kernel(const float* __restrict__ b0, const float* __restrict__ b1,
                   const float* __restrict__ b2, const float* __restrict__ b3,
                   int t0, int t1, int t2, int t3,
                   const float* __restrict__ maxg, const int* __restrict__ hard,
                   const int* __restrict__ kptr, float* __restrict__ out, int row0) {
    __shared__ __align__(16) unsigned samp[256];
    __shared__ __align__(16) unsigned cval[CCAP];
    __shared__ int cidx[CCAP];
    __shared__ int scnt[2][4];
    __shared__ int sbins[NCL];
    __shared__ unsigned spiv;
    __shared__ int ccnt;

    int t = threadIdx.x, w = t >> 6, l = t & 63;
    int li = blockIdx.x;               // panel-local row
    const float* qb[4] = {b0 + (size_t)li * t0, b1 + (size_t)li * t1,
                          b2 + (size_t)li * t2, b3 + (size_t)li * t3};

    if (t < NCL) sbins[t] = 0;
    if (t == 0) ccnt = 0;
    cval[t] = 0xFFFFFFFFu; cval[t + 256] = 0xFFFFFFFFu;   // pad: compares false
    cval[t + 512] = 0xFFFFFFFFu; cval[t + 768] = 0xFFFFFFFFu;
    samp[t] = ((const unsigned*)qb[1])[t];  // global cols 2048..2303
    __syncthreads();

    int topn = *kptr + 1;              // 26: thr = sorted[k]
    int r = topn / 16 + 1; if (r < 8) r = 8;  // sample rank: E[count] ~ 32r

    if (w == 0) {                      // wave-0 pivot search (4 samples/lane)
        uint4v sv = ((const uint4v*)samp)[l];
        unsigned lo = 0u, hi = 0x7F800000u;
        while (lo < hi) {              // wave-uniform
            unsigned mid = lo + ((hi - lo) >> 1);
            int c = 0;
#pragma unroll
            for (int e = 0; e < 4; ++e) c += __popcll(__ballot(sv[e] <= mid));
            if (c >= r) hi = mid; else lo = mid + 1;
        }
        if (l == 0) spiv = lo;
    }
    __syncthreads();
    unsigned piv = spiv;

    // segmented full-row pass: compact strict-< pivot candidates (value, index)
#pragma unroll
    for (int Q = 0; Q < 4; ++Q) {
        const uint4v* rq = (const uint4v*)qb[Q];
#pragma unroll
        for (int s = 0; s < 2; ++s) {
            uint4v u = rq[s * 256 + t];
#pragma unroll
            for (int c = 0; c < 4; ++c)
                if (u[c] < piv) {
                    int pos = atomicAdd(&ccnt, 1);
                    if (pos < CCAP) {
                        cval[pos] = u[c];
                        cidx[pos] = Q * PANEL + (s * 256 + t) * 4 + c;
                    }
                }
        }
    }
    __syncthreads();
    int nc = ccnt;
    bool ok = (nc >= topn) && (nc <= CCAP);

    unsigned thr;
    if (ok) {
        int pp = 0;
        unsigned lo = 0u, hi = piv;
        while (lo < hi) {
            unsigned mid = lo + ((hi - lo) >> 1);
            uint4v cv = ((const uint4v*)cval)[t];   // 1 b128/thread/probe
            int cnt = 0;
#pragma unroll
            for (int c = 0; c < 4; ++c) cnt += __popcll(__ballot(cv[c] <= mid));
            if (l == 0) scnt[pp][w] = cnt;
            __syncthreads();
            int tot = scnt[pp][0] + scnt[pp][1] + scnt[pp][2] + scnt[pp][3];
            if (tot >= topn) hi = mid; else lo = mid + 1;
            pp ^= 1;
        }
        thr = lo;
    } else {
        // exact fallback: segmented bisection over the full row (~never taken)
        int pp = 0;
        unsigned lo = 0u, hi = 0x7F800000u;
        while (lo < hi) {
            unsigned mid = lo + ((hi - lo) >> 1);
            int cnt = 0;
#pragma unroll
            for (int Q = 0; Q < 4; ++Q) {
                const uint4v* rq = (const uint4v*)qb[Q];
#pragma unroll
                for (int s = 0; s < 2; ++s) {
                    uint4v u = rq[s * 256 + t];
#pragma unroll
                    for (int c = 0; c < 4; ++c)
                        cnt += __popcll(__ballot(u[c] <= mid));
                }
            }
            if (l == 0) scnt[pp][w] = cnt;
            __syncthreads();
            int tot = scnt[pp][0] + scnt[pp][1] + scnt[pp][2] + scnt[pp][3];
            if (tot >= topn) hi = mid; else lo = mid + 1;
            pp ^= 1;
        }
        thr = lo;
    }

    // strict < thr -> per-cluster counts (candidates only on the fast path)
    if (ok) {
        for (int pos = t; pos < nc; pos += 256)
            if (cval[pos] < thr) atomicAdd(&sbins[hard[cidx[pos]]], 1);
    } else {
#pragma unroll
        for (int Q = 0; Q < 4; ++Q) {
            const uint4v* rq = (const uint4v*)qb[Q];
#pragma unroll
            for (int s = 0; s < 2; ++s) {
                uint4v u = rq[s * 256 + t];
#pragma unroll
                for (int c = 0; c < 4; ++c)
                    if (u[c] < thr)
                        atomicAdd(&sbins[hard[Q * PANEL + (s * 256 + t) * 4 + c]], 1);
            }
        }
    }
    __syncthreads();

    // entropy epilogue: wave 0, lanes 0..31 = clusters
    if (t < NCL) {
        int cnt = sbins[t];
        int n = cnt;
        for (int m = 16; m; m >>= 1) n += __shfl_xor(n, m, 64);
        float nf = (float)n;
        float b = (float)cnt / nf;
        float term = -b * logf(b + 1e-5f);
        for (int m = 16; m; m >>= 1) term += __shfl_xor(term, m, 64);
        if (t == 0) out[row0 + li] = term * maxg[row0 + li];
    }
}

extern "C" void kernel_launch(void* const* d_in, const int* in_sizes, int n_in,
                              void* d_out, int out_size, void* d_ws, size_t ws_size,
                              hipStream_t stream) {
    const float* enc = (const float*)d_in[0];
    const float* cat = (const float*)d_in[1];
    const int* kptr = (const int*)d_in[2];
    float* out = (float*)d_out;

    float* sq = (float*)d_ws;
    float* maxg = sq + BN;
    int* hard = (int*)(maxg + BN);
    ushort* eh = (ushort*)(hard + BN);
    ushort* el = eh + (size_t)BN * ENC;
    float* live = (float*)(el + (size_t)BN * ENC);            // 2048 x 8192 = 64 MB
    float* stash = live + (size_t)PANEL * BN;                 // 6 x 2048^2 = 96 MB

    prep_kernel<<<BN / 4, 256, 0, stream>>>(enc, cat, sq, maxg, hard, eh, el);

    for (int p = 0; p < 4; ++p) {
        int nwg = 136 + (3 - p) * 256;    // upper-tri diag tiles + off-diag blocks
        dist_mfma_kernel<<<nwg, 256, 0, stream>>>(eh, el, sq, live, stash, p);

        const float* b[4]; int st[4];
        for (int q = 0; q < 4; ++q) {
            if (q < p) {
                b[q] = stash + (size_t)(p * (p - 1) / 2 + q) * ((size_t)PANEL * PANEL);
                st[q] = PANEL;
            } else {
                b[q] = live + (size_t)q * PANEL;
                st[q] = BN;
            }
        }
        select_kernel<<<PANEL, 256, 0, stream>>>(b[0], b[1], b[2], b[3],
                                                 st[0], st[1], st[2], st[3],
                                                 maxg, hard, kptr, out, p * PANEL);
    }
}